// Round 2
// baseline (104.456 us; speedup 1.0000x reference)
//
#include <hip/hip_runtime.h>

// ---------------------------------------------------------------------------
// Adapter: LayerNorm(2048) -> down(64) -> ReLU -> up(2048), 16384 tokens fp32.
// LN folded into down-proj (x read once):
//   down[n] = rstd*( dot(wg[n],x) - mu*s[n] ) + c[n],  wg = bf16(w_down*gamma)
// R2: occupancy fix. One block (4 waves) per 16-row tile -> 1024 blocks,
// 4 waves/SIMD (was 1). K split 4-way in down phase (LDS reduce); up phase
// columns split 4-way; up-GEMM operand-swapped so stores are f32x4.
// ---------------------------------------------------------------------------

typedef __attribute__((ext_vector_type(8))) short short8;   // 8 x bf16
typedef __attribute__((ext_vector_type(4))) float f32x4;

#define D_MODEL 2048
#define BNECK   64
#define EPS     1e-5f

__device__ inline short f2bf(float f) {
    unsigned int u = __builtin_bit_cast(unsigned int, f);
    unsigned int r = (u + 0x7fffu + ((u >> 16) & 1u)) >> 16;   // RNE
    return (short)r;
}
__device__ inline float bf2f(short s) {
    unsigned int u = ((unsigned int)(unsigned short)s) << 16;
    return __builtin_bit_cast(float, u);
}

// ---------------------------------------------------------------------------
// Prep: wg = bf16(w_down*gamma) [64x2048], s[n]=sum(wg[n,:]),
// c[n]=sum(w_down[n,:]*beta)+b_down[n], wupb = bf16(w_up) [2048x64].
// ---------------------------------------------------------------------------
__global__ __launch_bounds__(256) void prep_kernel(
    const float* __restrict__ w_down, const float* __restrict__ gamma,
    const float* __restrict__ beta,   const float* __restrict__ b_down,
    const float* __restrict__ w_up,
    short* __restrict__ wg, short* __restrict__ wupb,
    float* __restrict__ s_out, float* __restrict__ c_out)
{
    __shared__ float rs[4], rc[4];
    int b = blockIdx.x;
    if (b < BNECK) {
        int n = b;
        float ps = 0.f, pc = 0.f;
        for (int d = threadIdx.x; d < D_MODEL; d += 256) {
            float wv  = w_down[n * D_MODEL + d];
            short h   = f2bf(wv * gamma[d]);
            wg[n * D_MODEL + d] = h;
            ps += bf2f(h);                       // consistent with bf16 dot
            pc  = fmaf(wv, beta[d], pc);
        }
        for (int o = 32; o > 0; o >>= 1) {
            ps += __shfl_down(ps, o, 64);
            pc += __shfl_down(pc, o, 64);
        }
        int wid = threadIdx.x >> 6, lane = threadIdx.x & 63;
        if (lane == 0) { rs[wid] = ps; rc[wid] = pc; }
        __syncthreads();
        if (threadIdx.x == 0) {
            s_out[n] = rs[0] + rs[1] + rs[2] + rs[3];
            c_out[n] = rc[0] + rc[1] + rc[2] + rc[3] + b_down[n];
        }
    } else {
        for (int i = (b - BNECK) * 256 + threadIdx.x; i < D_MODEL * BNECK;
             i += 64 * 256)
            wupb[i] = f2bf(w_up[i]);
    }
}

// ---------------------------------------------------------------------------
// Main fused kernel. 1024 blocks x 256 threads; block owns one 16-row tile.
// ---------------------------------------------------------------------------
__global__ __launch_bounds__(256) void adapter_kernel(
    const float* __restrict__ x,    const float* __restrict__ b_up,
    const short* __restrict__ wg,   const short* __restrict__ wup,
    const float* __restrict__ s_v,  const float* __restrict__ c_v,
    float* __restrict__ out)
{
    __shared__ __align__(16) float red[4][64][20];   // 20480 B cross-wave acc
    __shared__ __align__(16) char  tile[2048];       // 16x64 bf16, XOR-swizzled

    const int wid  = threadIdx.x >> 6;
    const int lane = threadIdx.x & 63;
    const int r    = lane & 15;        // A-row / B-col within fragment
    const int g    = lane >> 4;        // k-group
    const int row0 = blockIdx.x * 16;

    // ---- Phase 1: down-GEMM, K slice [wid*512, wid*512+512) ----------------
    const float* xr  = x  + (size_t)(row0 + r) * D_MODEL + wid * 512 + g * 8;
    const short* wgl = wg + r * D_MODEL + wid * 512 + g * 8;

    f32x4 acc[4];
#pragma unroll
    for (int nf = 0; nf < 4; ++nf) acc[nf] = (f32x4){0.f, 0.f, 0.f, 0.f};
    float sum = 0.f, sq = 0.f;

#pragma unroll 4
    for (int kb = 0; kb < 512; kb += 32) {
        f32x4 xa = *(const f32x4*)(xr + kb);
        f32x4 xb = *(const f32x4*)(xr + kb + 4);

        sum += ((xa.x + xa.y) + (xa.z + xa.w)) +
               ((xb.x + xb.y) + (xb.z + xb.w));
        sq = fmaf(xa.x, xa.x, sq); sq = fmaf(xa.y, xa.y, sq);
        sq = fmaf(xa.z, xa.z, sq); sq = fmaf(xa.w, xa.w, sq);
        sq = fmaf(xb.x, xb.x, sq); sq = fmaf(xb.y, xb.y, sq);
        sq = fmaf(xb.z, xb.z, sq); sq = fmaf(xb.w, xb.w, sq);

        short8 af;
        af[0] = f2bf(xa.x); af[1] = f2bf(xa.y); af[2] = f2bf(xa.z); af[3] = f2bf(xa.w);
        af[4] = f2bf(xb.x); af[5] = f2bf(xb.y); af[6] = f2bf(xb.z); af[7] = f2bf(xb.w);

        short8 b0 = *(const short8*)(wgl + kb);
        short8 b1 = *(const short8*)(wgl + 16 * D_MODEL + kb);
        short8 b2 = *(const short8*)(wgl + 32 * D_MODEL + kb);
        short8 b3 = *(const short8*)(wgl + 48 * D_MODEL + kb);
        acc[0] = __builtin_amdgcn_mfma_f32_16x16x32_bf16(af, b0, acc[0], 0, 0, 0);
        acc[1] = __builtin_amdgcn_mfma_f32_16x16x32_bf16(af, b1, acc[1], 0, 0, 0);
        acc[2] = __builtin_amdgcn_mfma_f32_16x16x32_bf16(af, b2, acc[2], 0, 0, 0);
        acc[3] = __builtin_amdgcn_mfma_f32_16x16x32_bf16(af, b3, acc[3], 0, 0, 0);
    }

    // ---- cross-wave reduce of partial accs + LN stats ----------------------
    float* myred = &red[wid][lane][0];
    *(f32x4*)(myred +  0) = acc[0];
    *(f32x4*)(myred +  4) = acc[1];
    *(f32x4*)(myred +  8) = acc[2];
    *(f32x4*)(myred + 12) = acc[3];
    myred[16] = sum; myred[17] = sq;
    __syncthreads();

    f32x4 accw = (f32x4){0.f, 0.f, 0.f, 0.f};   // this wave owns frag nf=wid
    float tsum = 0.f, tsq = 0.f;
#pragma unroll
    for (int w2 = 0; w2 < 4; ++w2) {
        const float* p = &red[w2][lane][0];
        accw += *(const f32x4*)(p + wid * 4);
        tsum += p[16]; tsq += p[17];
    }

    tsum += __shfl_xor(tsum, 16, 64); tsum += __shfl_xor(tsum, 32, 64);
    tsq  += __shfl_xor(tsq , 16, 64); tsq  += __shfl_xor(tsq , 32, 64);
    float mu_r   = tsum * (1.f / D_MODEL);
    float var    = tsq * (1.f / D_MODEL) - mu_r * mu_r;
    float rstd_r = rsqrtf(var + EPS);

    float mu_m[4], rs_m[4];
#pragma unroll
    for (int reg = 0; reg < 4; ++reg) {
        int m = g * 4 + reg;
        mu_m[reg] = __shfl(mu_r, m, 64);
        rs_m[reg] = __shfl(rstd_r, m, 64);
    }

    // ---- fix-up + ReLU for this wave's 16-col slice of the down tile -------
    {
        int   n  = wid * 16 + r;
        float sn = s_v[n], cn = c_v[n];
#pragma unroll
        for (int reg = 0; reg < 4; ++reg) {
            int   m = g * 4 + reg;
            float v = fmaf(rs_m[reg], accw[reg] - mu_m[reg] * sn, cn);
            v = fmaxf(v, 0.f);
            int off = ((m * 64 + n) * 2) ^ ((m & 7) << 4);
            *(short*)(tile + off) = f2bf(v);
        }
    }
    __syncthreads();

    // ---- Phase 2: up-GEMM, operand-swapped (A=w_up, B=down^T) --------------
    // D[d_local][token]: lane holds token=r, d=dbase+g*4+reg -> f32x4 store.
    short8 bd0 = *(const short8*)(tile + ((r * 128 +  0 + g * 16) ^ ((r & 7) << 4)));
    short8 bd1 = *(const short8*)(tile + ((r * 128 + 64 + g * 16) ^ ((r & 7) << 4)));

    const short* wupl = wup + r * BNECK + g * 8;
    float* outr = out + (size_t)(row0 + r) * D_MODEL;

#pragma unroll 4
    for (int i = 0; i < 32; ++i) {
        int dbase = (wid * 32 + i) * 16;
        short8 a0 = *(const short8*)(wupl + dbase * BNECK);
        short8 a1 = *(const short8*)(wupl + dbase * BNECK + 32);
        f32x4 o = (f32x4){0.f, 0.f, 0.f, 0.f};
        o = __builtin_amdgcn_mfma_f32_16x16x32_bf16(a0, bd0, o, 0, 0, 0);
        o = __builtin_amdgcn_mfma_f32_16x16x32_bf16(a1, bd1, o, 0, 0, 0);
        f32x4 bu = *(const f32x4*)(b_up + dbase + g * 4);
        o += bu;
        *(f32x4*)(outr + dbase + g * 4) = o;
    }
}

extern "C" void kernel_launch(void* const* d_in, const int* in_sizes, int n_in,
                              void* d_out, int out_size, void* d_ws, size_t ws_size,
                              hipStream_t stream) {
    const float* x      = (const float*)d_in[0];
    const float* gamma  = (const float*)d_in[1];
    const float* beta   = (const float*)d_in[2];
    const float* w_down = (const float*)d_in[3];
    const float* b_down = (const float*)d_in[4];
    const float* w_up   = (const float*)d_in[5];
    const float* b_up   = (const float*)d_in[6];
    float* out = (float*)d_out;

    char* ws = (char*)d_ws;
    short* wg   = (short*)ws;                    // 64*2048*2   = 262144 B
    short* wupb = (short*)(ws + 262144);         // 2048*64*2   = 262144 B
    float* s_v  = (float*)(ws + 524288);         // 256 B
    float* c_v  = (float*)(ws + 524544);         // 256 B

    prep_kernel<<<128, 256, 0, stream>>>(w_down, gamma, beta, b_down, w_up,
                                         wg, wupb, s_v, c_v);
    adapter_kernel<<<1024, 256, 0, stream>>>(x, b_up, wg, wupb, s_v, c_v, out);
}

// Round 4
// 76.152 us; speedup vs baseline: 1.3717x; 1.3717x over previous
//
#include <hip/hip_runtime.h>

// ---------------------------------------------------------------------------
// Adapter: LayerNorm(2048) -> down(64) -> ReLU -> up(2048), 16384 tokens fp32.
// LN folded into down-proj (x read once):
//   down[n] = rstd*( dot(wg[n],x) - mu*s[n] ) + c[n],  wg = bf16(w_down*gamma)
// R4 = R3 with two fixes:
//  1) BUG: x-stage LDS read swizzle must XOR the FULL byte offset
//     ((cb+16)^swz, not (cb^swz)+16) -- odd rows read wrong halves in R3.
//  2) wg fragments software-pipelined one chunk ahead (reg double-buffer),
//     so vmcnt(12) keeps {STAGE(c+1), wg[c+1]} in flight instead of
//     serializing the staging DMA behind same-iteration weight loads.
// ---------------------------------------------------------------------------

typedef __attribute__((ext_vector_type(8))) short short8;   // 8 x bf16
typedef __attribute__((ext_vector_type(4))) float f32x4;

#define D_MODEL 2048
#define BNECK   64
#define EPS     1e-5f

__device__ inline short f2bf(float f) {
    unsigned int u = __builtin_bit_cast(unsigned int, f);
    unsigned int r = (u + 0x7fffu + ((u >> 16) & 1u)) >> 16;   // RNE
    return (short)r;
}
__device__ inline float bf2f(short s) {
    unsigned int u = ((unsigned int)(unsigned short)s) << 16;
    return __builtin_bit_cast(float, u);
}

// ---------------------------------------------------------------------------
// Prep. wg_perm: fragment-major bf16(w_down*gamma): slot (t*4+nf) holds the
// wave-fragment for k-step t (K=32) and n-block nf; lane l's 8 bf16 at
// slot*512 + l*8 are (n = nf*16+(l&15), k = t*32+(l>>4)*8 + e).
// wup_perm: slot (b16*2+h): lane l -> (d = b16*16+(l&15), kn = h*32+(l>>4)*8+e).
// s[n] = sum_k wg (bf16-rounded), c[n] = w_down[n,:].beta + b_down[n].
// ---------------------------------------------------------------------------
__global__ __launch_bounds__(256) void prep_kernel(
    const float* __restrict__ w_down, const float* __restrict__ gamma,
    const float* __restrict__ beta,   const float* __restrict__ b_down,
    const float* __restrict__ w_up,
    short* __restrict__ wg_perm, short* __restrict__ wup_perm,
    float* __restrict__ s_out, float* __restrict__ c_out)
{
    __shared__ float rs[4], rc[4];
    int b = blockIdx.x;
    if (b < BNECK) {
        int n = b, nf = n >> 4;
        float ps = 0.f, pc = 0.f;
        for (int d = threadIdx.x; d < D_MODEL; d += 256) {
            float wv = w_down[n * D_MODEL + d];
            short h  = f2bf(wv * gamma[d]);
            int t = d >> 5, kg = (d >> 3) & 3, e = d & 7;
            int l = kg * 16 + (n & 15);
            wg_perm[(size_t)((t * 4 + nf) * 64 + l) * 8 + e] = h;
            ps += bf2f(h);
            pc  = fmaf(wv, beta[d], pc);
        }
        for (int o = 32; o > 0; o >>= 1) {
            ps += __shfl_down(ps, o, 64);
            pc += __shfl_down(pc, o, 64);
        }
        int wid = threadIdx.x >> 6, lane = threadIdx.x & 63;
        if (lane == 0) { rs[wid] = ps; rc[wid] = pc; }
        __syncthreads();
        if (threadIdx.x == 0) {
            s_out[n] = rs[0] + rs[1] + rs[2] + rs[3];
            c_out[n] = rc[0] + rc[1] + rc[2] + rc[3] + b_down[n];
        }
    } else {
        for (int j = (b - BNECK) * 256 + threadIdx.x; j < D_MODEL * BNECK;
             j += 64 * 256) {
            int d = j >> 6, kn = j & 63;
            int b16 = d >> 4, h2 = kn >> 5, e = kn & 7;
            int l = ((kn >> 3) & 3) * 16 + (d & 15);
            wup_perm[(size_t)((b16 * 2 + h2) * 64 + l) * 8 + e] = f2bf(w_up[j]);
        }
    }
}

struct W8 { short8 w[8]; };

// ---------------------------------------------------------------------------
// Main kernel. 1024 blocks x 256 threads; block owns 16 rows; waves K-split.
// ---------------------------------------------------------------------------
__global__ __launch_bounds__(256, 4) void adapter_kernel(
    const float* __restrict__ x,    const float* __restrict__ b_up,
    const short* __restrict__ wg_perm, const short* __restrict__ wup_perm,
    const float* __restrict__ s_v,  const float* __restrict__ c_v,
    float* __restrict__ out)
{
    __shared__ __align__(16) char xstage[4][2][4096];  // per-wave dbuf, 32 KB
    __shared__ __align__(16) char tilebuf[2048];       // 16x64 bf16, swizzled
    float (*red)[64][20] = reinterpret_cast<float(*)[64][20]>(&xstage[0][0][0]);

    const int wid  = threadIdx.x >> 6;
    const int lane = threadIdx.x & 63;
    const int r    = lane & 15;        // frag row/col index
    const int g    = lane >> 4;        // k-group
    const int row0 = blockIdx.x * 16;
    const char* xbase = (const char*)x;
    const int swz = (r & 7) << 4;

    // stage chunk c (16 rows x 64 f32) into per-wave buffer `buf`;
    // LDS dest linear (lane*16B), global source pre-swizzled (involution).
    auto STAGE = [&](int c, int buf) {
#pragma unroll
        for (int i = 0; i < 4; ++i) {
            int rowl = i * 4 + g;
            const char* src = xbase +
                (((size_t)(row0 + rowl) * D_MODEL + wid * 512 + c * 64) << 2) +
                ((r * 16) ^ ((rowl & 7) << 4));
            __builtin_amdgcn_global_load_lds(
                (const __attribute__((address_space(1))) void*)src,
                (__attribute__((address_space(3))) void*)(&xstage[wid][buf][i * 1024]),
                16, 0, 0);
        }
    };
    // fragment-major wg for chunk c: 8 x 1KB fully-coalesced loads
    auto LOADW = [&](int c) {
        W8 o;
        const short* p = wg_perm + ((size_t)(wid * 16 + c * 2) * 4) * 512
                       + lane * 8;
#pragma unroll
        for (int k = 0; k < 8; ++k) o.w[k] = *(const short8*)(p + k * 512);
        return o;
    };

    f32x4 acc[4];
#pragma unroll
    for (int nf = 0; nf < 4; ++nf) acc[nf] = (f32x4){0.f, 0.f, 0.f, 0.f};
    float sum = 0.f, sq = 0.f;

    STAGE(0, 0);
    W8 wcur = LOADW(0), wnxt;

    // ---- down-GEMM: 8 chunks of K=64 over this wave's 512-wide K slice ----
#pragma unroll
    for (int c = 0; c < 8; ++c) {
        const int buf = c & 1;
        if (c < 7) {
            STAGE(c + 1, buf ^ 1);
            wnxt = LOADW(c + 1);
            // wait: {STAGE(c), wg[c]} done; {STAGE(c+1), wg[c+1]} in flight
            asm volatile("s_waitcnt vmcnt(12)" ::: "memory");
        } else {
            asm volatile("s_waitcnt vmcnt(0)" ::: "memory");
        }
        const char* bp = &xstage[wid][buf][0];
#pragma unroll
        for (int kb = 0; kb < 2; ++kb) {
            int cb = kb * 128 + g * 32;
            f32x4 xa = *(const f32x4*)(bp + r * 256 + ( cb        ^ swz));
            f32x4 xb = *(const f32x4*)(bp + r * 256 + ((cb + 16)  ^ swz));
            sum += ((xa.x + xa.y) + (xa.z + xa.w)) +
                   ((xb.x + xb.y) + (xb.z + xb.w));
            sq = fmaf(xa.x, xa.x, sq); sq = fmaf(xa.y, xa.y, sq);
            sq = fmaf(xa.z, xa.z, sq); sq = fmaf(xa.w, xa.w, sq);
            sq = fmaf(xb.x, xb.x, sq); sq = fmaf(xb.y, xb.y, sq);
            sq = fmaf(xb.z, xb.z, sq); sq = fmaf(xb.w, xb.w, sq);
            short8 af;
            af[0] = f2bf(xa.x); af[1] = f2bf(xa.y);
            af[2] = f2bf(xa.z); af[3] = f2bf(xa.w);
            af[4] = f2bf(xb.x); af[5] = f2bf(xb.y);
            af[6] = f2bf(xb.z); af[7] = f2bf(xb.w);
            acc[0] = __builtin_amdgcn_mfma_f32_16x16x32_bf16(af, wcur.w[kb*4+0], acc[0], 0, 0, 0);
            acc[1] = __builtin_amdgcn_mfma_f32_16x16x32_bf16(af, wcur.w[kb*4+1], acc[1], 0, 0, 0);
            acc[2] = __builtin_amdgcn_mfma_f32_16x16x32_bf16(af, wcur.w[kb*4+2], acc[2], 0, 0, 0);
            acc[3] = __builtin_amdgcn_mfma_f32_16x16x32_bf16(af, wcur.w[kb*4+3], acc[3], 0, 0, 0);
        }
        if (c < 7) wcur = wnxt;
    }

    // ---- cross-wave K-reduce (red aliases the staging buffers) ------------
    __syncthreads();                       // all waves done with xstage
    float* myred = &red[wid][lane][0];
    *(f32x4*)(myred +  0) = acc[0];
    *(f32x4*)(myred +  4) = acc[1];
    *(f32x4*)(myred +  8) = acc[2];
    *(f32x4*)(myred + 12) = acc[3];
    myred[16] = sum; myred[17] = sq;
    __syncthreads();

    f32x4 accw = (f32x4){0.f, 0.f, 0.f, 0.f};   // this wave owns frag nf=wid
    float tsum = 0.f, tsq = 0.f;
#pragma unroll
    for (int w2 = 0; w2 < 4; ++w2) {
        const float* p = &red[w2][lane][0];
        accw += *(const f32x4*)(p + wid * 4);
        tsum += p[16]; tsq += p[17];
    }

    tsum += __shfl_xor(tsum, 16, 64); tsum += __shfl_xor(tsum, 32, 64);
    tsq  += __shfl_xor(tsq , 16, 64); tsq  += __shfl_xor(tsq , 32, 64);
    float mu_r   = tsum * (1.f / D_MODEL);
    float var    = tsq * (1.f / D_MODEL) - mu_r * mu_r;
    float rstd_r = rsqrtf(var + EPS);

    float mu_m[4], rs_m[4];
#pragma unroll
    for (int reg = 0; reg < 4; ++reg) {
        int m = g * 4 + reg;
        mu_m[reg] = __shfl(mu_r, m, 64);
        rs_m[reg] = __shfl(rstd_r, m, 64);
    }

    // ---- fix-up + ReLU into the shared 16x64 tile -------------------------
    {
        int   n  = wid * 16 + r;
        float sn = s_v[n], cn = c_v[n];
#pragma unroll
        for (int reg = 0; reg < 4; ++reg) {
            int   m = g * 4 + reg;
            float v = fmaf(rs_m[reg], accw[reg] - mu_m[reg] * sn, cn);
            v = fmaxf(v, 0.f);
            *(short*)(tilebuf + ((m * 128 + n * 2) ^ ((m & 7) << 4))) = f2bf(v);
        }
    }
    __syncthreads();

    // ---- up-GEMM (A = w_up fragment-major, B = down^T) --------------------
    short8 bd0 = *(const short8*)(tilebuf + ((r * 128 +  0 + g * 16) ^ swz));
    short8 bd1 = *(const short8*)(tilebuf + ((r * 128 + 64 + g * 16) ^ swz));

    const short* wupl = wup_perm + lane * 8;
    float* outr = out + (size_t)(row0 + r) * D_MODEL;

#pragma unroll 4
    for (int i = 0; i < 32; ++i) {
        int b16 = wid * 32 + i;
        short8 a0 = *(const short8*)(wupl + (size_t)(b16 * 2 + 0) * 512);
        short8 a1 = *(const short8*)(wupl + (size_t)(b16 * 2 + 1) * 512);
        f32x4 o = (f32x4){0.f, 0.f, 0.f, 0.f};
        o = __builtin_amdgcn_mfma_f32_16x16x32_bf16(a0, bd0, o, 0, 0, 0);
        o = __builtin_amdgcn_mfma_f32_16x16x32_bf16(a1, bd1, o, 0, 0, 0);
        int dbase = b16 * 16;
        f32x4 bu = *(const f32x4*)(b_up + dbase + g * 4);
        o += bu;
        *(f32x4*)(outr + dbase + g * 4) = o;
    }
}

extern "C" void kernel_launch(void* const* d_in, const int* in_sizes, int n_in,
                              void* d_out, int out_size, void* d_ws, size_t ws_size,
                              hipStream_t stream) {
    const float* x      = (const float*)d_in[0];
    const float* gamma  = (const float*)d_in[1];
    const float* beta   = (const float*)d_in[2];
    const float* w_down = (const float*)d_in[3];
    const float* b_down = (const float*)d_in[4];
    const float* w_up   = (const float*)d_in[5];
    const float* b_up   = (const float*)d_in[6];
    float* out = (float*)d_out;

    char* ws = (char*)d_ws;
    short* wg_perm  = (short*)ws;                 // 256 KB
    short* wup_perm = (short*)(ws + 262144);      // 256 KB
    float* s_v  = (float*)(ws + 524288);          // 256 B
    float* c_v  = (float*)(ws + 524544);          // 256 B

    prep_kernel<<<128, 256, 0, stream>>>(w_down, gamma, beta, b_down, w_up,
                                         wg_perm, wup_perm, s_v, c_v);
    adapter_kernel<<<1024, 256, 0, stream>>>(x, b_up, wg_perm, wup_perm,
                                             s_v, c_v, out);
}

// Round 5
// 67.989 us; speedup vs baseline: 1.5364x; 1.1201x over previous
//
#include <hip/hip_runtime.h>

// ---------------------------------------------------------------------------
// Adapter: LayerNorm(2048) -> down(64) -> ReLU -> up(2048), 16384 tokens fp32.
// LN folded into down-proj (x read once):
//   down[n] = rstd*( dot(wg[n],x) - mu*s[n] ) + c[n],  wg = bf16(w_down*gamma)
// R5: n-split waves (each wave owns 16 of 64 n over FULL K):
//  - no cross-wave accumulator reduce (acc complete per wave)
//  - x staged block-cooperatively, register-staged 3 chunks deep, ONE raw
//    s_barrier per chunk, no vmcnt(0) drains in the loop
//  - LN stats from each wave's own staged registers (4 rows/wave)
//  - LDS 10.4KB, ~90 VGPR -> up phase gets a 2-deep wup register pipeline
// ---------------------------------------------------------------------------

typedef __attribute__((ext_vector_type(8))) short short8;   // 8 x bf16
typedef __attribute__((ext_vector_type(4))) float f32x4;

#define D_MODEL 2048
#define BNECK   64
#define EPS     1e-5f
#define NCHUNK  32          // chunks of K=64 (256B per row)

__device__ inline short f2bf(float f) {
    unsigned int u = __builtin_bit_cast(unsigned int, f);
    unsigned int r = (u + 0x7fffu + ((u >> 16) & 1u)) >> 16;   // RNE
    return (short)r;
}
__device__ inline float bf2f(short s) {
    unsigned int u = ((unsigned int)(unsigned short)s) << 16;
    return __builtin_bit_cast(float, u);
}

// ---------------------------------------------------------------------------
// Prep. wg_perm slot = (n>>4)*64 + (k>>5): per-wave contiguous 64KB stream.
// Within slot: lane l = ((k>>3)&3)*16 + (n&15), elem e = k&7.
// wup_perm: slot (b16*2+h): lane l -> (d=b16*16+(l&15), kn=h*32+(l>>4)*8+e).
// s[n] = sum_k bf16(wg), c[n] = w_down[n,:].beta + b_down[n].
// ---------------------------------------------------------------------------
__global__ __launch_bounds__(256) void prep_kernel(
    const float* __restrict__ w_down, const float* __restrict__ gamma,
    const float* __restrict__ beta,   const float* __restrict__ b_down,
    const float* __restrict__ w_up,
    short* __restrict__ wg_perm, short* __restrict__ wup_perm,
    float* __restrict__ s_out, float* __restrict__ c_out)
{
    __shared__ float rs[4], rc[4];
    int b = blockIdx.x;
    if (b < BNECK) {
        int n = b, nf = n >> 4;
        float ps = 0.f, pc = 0.f;
        for (int d = threadIdx.x; d < D_MODEL; d += 256) {
            float wv = w_down[n * D_MODEL + d];
            short h  = f2bf(wv * gamma[d]);
            int t = d >> 5, kg = (d >> 3) & 3, e = d & 7;
            int l = kg * 16 + (n & 15);
            wg_perm[(size_t)((nf * 64 + t) * 64 + l) * 8 + e] = h;
            ps += bf2f(h);
            pc  = fmaf(wv, beta[d], pc);
        }
        for (int o = 32; o > 0; o >>= 1) {
            ps += __shfl_down(ps, o, 64);
            pc += __shfl_down(pc, o, 64);
        }
        int wid = threadIdx.x >> 6, lane = threadIdx.x & 63;
        if (lane == 0) { rs[wid] = ps; rc[wid] = pc; }
        __syncthreads();
        if (threadIdx.x == 0) {
            s_out[n] = rs[0] + rs[1] + rs[2] + rs[3];
            c_out[n] = rc[0] + rc[1] + rc[2] + rc[3] + b_down[n];
        }
    } else {
        for (int j = (b - BNECK) * 256 + threadIdx.x; j < D_MODEL * BNECK;
             j += 64 * 256) {
            int d = j >> 6, kn = j & 63;
            int b16 = d >> 4, h2 = kn >> 5, e = kn & 7;
            int l = ((kn >> 3) & 3) * 16 + (d & 15);
            wup_perm[(size_t)((b16 * 2 + h2) * 64 + l) * 8 + e] = f2bf(w_up[j]);
        }
    }
}

// ---------------------------------------------------------------------------
// Main kernel. 1024 blocks x 256 threads; block owns 16 tokens; waves n-split.
// ---------------------------------------------------------------------------
__global__ __launch_bounds__(256, 4) void adapter_kernel(
    const float* __restrict__ x,    const float* __restrict__ b_up,
    const short* __restrict__ wg_perm, const short* __restrict__ wup_perm,
    const float* __restrict__ s_v,  const float* __restrict__ c_v,
    float* __restrict__ out)
{
    __shared__ __align__(16) char xbuf[2][4096];   // shared dbuf: 16 rows x 256B
    __shared__ __align__(16) char tilebuf[2048];   // 16x64 bf16, swizzled
    __shared__ float stats2[16][2];                // per-token (mu, rstd)

    const int wid  = threadIdx.x >> 6;
    const int lane = threadIdx.x & 63;
    const int r    = lane & 15;          // frag row/col index
    const int g    = lane >> 4;          // k-group
    const int row0 = blockIdx.x * 16;
    const int swz  = (r & 7) << 4;

    // ---- cooperative staging: wave wid owns rows [wid*4, wid*4+4) ---------
    const int srow = wid * 4 + g;                  // this lane's staged row
    const int scol = r * 16;                       // byte col within 256B chunk
    const char* xsrc = (const char*)x
        + ((size_t)(row0 + srow) * D_MODEL) * 4 + scol;
    char* const swdst = &xbuf[0][0] + srow * 256 + (scol ^ ((srow & 7) << 4));

    const short* wbase = wg_perm + (size_t)(wid * 64) * 512 + lane * 8;

    f32x4  xr[4];            // register-staged x chunks (3 in flight)
    short8 wb[2][2];         // weight frags, 1 chunk ahead
    f32x4  acc = (f32x4){0.f, 0.f, 0.f, 0.f};
    float  ssum = 0.f, ssq = 0.f;

    auto LDX = [&](int c) { return *(const f32x4*)(xsrc + c * 256); };
    auto LDW = [&](int c, short8* w) {
        w[0] = *(const short8*)(wbase + (size_t)(c * 2 + 0) * 512);
        w[1] = *(const short8*)(wbase + (size_t)(c * 2 + 1) * 512);
    };
    auto STATS_WRITE = [&](int c, const f32x4& v) {   // stats + publish to LDS
        ssum += (v.x + v.y) + (v.z + v.w);
        ssq = fmaf(v.x, v.x, ssq); ssq = fmaf(v.y, v.y, ssq);
        ssq = fmaf(v.z, v.z, ssq); ssq = fmaf(v.w, v.w, ssq);
        *(f32x4*)(swdst + (size_t)(c & 1) * 4096) = v;    // ds_write_b128
    };

    // prologue: 3 chunks of x in flight, weights 1 chunk ahead
    xr[0] = LDX(0); xr[1] = LDX(1); xr[2] = LDX(2);
    LDW(0, wb[0]);
    STATS_WRITE(0, xr[0]);

#pragma unroll
    for (int c = 0; c < NCHUNK; ++c) {
        if (c + 3 < NCHUNK) xr[(c + 3) & 3] = LDX(c + 3);
        if (c + 1 < NCHUNK) LDW(c + 1, wb[(c + 1) & 1]);
        // publish writes of chunk c, certify reads of buf[(c+1)&1] finished
        asm volatile("s_waitcnt lgkmcnt(0)\n\ts_barrier" ::: "memory");
        if (c + 1 < NCHUNK) STATS_WRITE(c + 1, xr[(c + 1) & 3]);

        const char* bp = &xbuf[c & 1][0];
        const short8* w = wb[c & 1];
#pragma unroll
        for (int kb = 0; kb < 2; ++kb) {
            int cb = kb * 128 + g * 32;
            f32x4 xa = *(const f32x4*)(bp + r * 256 + ( cb        ^ swz));
            f32x4 xb = *(const f32x4*)(bp + r * 256 + ((cb + 16)  ^ swz));
            short8 af;
            af[0] = f2bf(xa.x); af[1] = f2bf(xa.y);
            af[2] = f2bf(xa.z); af[3] = f2bf(xa.w);
            af[4] = f2bf(xb.x); af[5] = f2bf(xb.y);
            af[6] = f2bf(xb.z); af[7] = f2bf(xb.w);
            acc = __builtin_amdgcn_mfma_f32_16x16x32_bf16(af, w[kb], acc, 0, 0, 0);
        }
    }

    // ---- LN stats for this wave's 4 staged rows (reduce over 16 lanes) ----
#pragma unroll
    for (int m = 1; m < 16; m <<= 1) {
        ssum += __shfl_xor(ssum, m, 64);
        ssq  += __shfl_xor(ssq , m, 64);
    }
    float mu   = ssum * (1.f / D_MODEL);
    float rstd = rsqrtf(ssq * (1.f / D_MODEL) - mu * mu + EPS);
    if (r == 0) { stats2[srow][0] = mu; stats2[srow][1] = rstd; }
    __syncthreads();

    // ---- fix-up + ReLU: wave owns n = wid*16 + r, tokens m = g*4+reg ------
    {
        int   n  = wid * 16 + r;
        float sn = s_v[n], cn = c_v[n];
#pragma unroll
        for (int reg = 0; reg < 4; ++reg) {
            int   m = g * 4 + reg;
            float v = fmaf(stats2[m][1], acc[reg] - stats2[m][0] * sn, cn);
            v = fmaxf(v, 0.f);
            *(short*)(tilebuf + ((m * 128 + n * 2) ^ ((m & 7) << 4))) = f2bf(v);
        }
    }
    __syncthreads();

    // ---- up-GEMM (A = w_up fragment-major, B = down^T), 2-deep pipeline ---
    short8 bd0 = *(const short8*)(tilebuf + ((r * 128 +  0 + g * 16) ^ swz));
    short8 bd1 = *(const short8*)(tilebuf + ((r * 128 + 64 + g * 16) ^ swz));

    const short* wupl = wup_perm + lane * 8;
    float* outr = out + (size_t)(row0 + r) * D_MODEL;

    short8 ua[2], ub[2];
    {
        int b16 = wid * 32;
        ua[0] = *(const short8*)(wupl + (size_t)(b16 * 2 + 0) * 512);
        ub[0] = *(const short8*)(wupl + (size_t)(b16 * 2 + 1) * 512);
    }
#pragma unroll
    for (int i = 0; i < 32; ++i) {
        int cur = i & 1;
        if (i < 31) {
            int b16 = wid * 32 + i + 1;
            ua[cur ^ 1] = *(const short8*)(wupl + (size_t)(b16 * 2 + 0) * 512);
            ub[cur ^ 1] = *(const short8*)(wupl + (size_t)(b16 * 2 + 1) * 512);
        }
        f32x4 o = (f32x4){0.f, 0.f, 0.f, 0.f};
        o = __builtin_amdgcn_mfma_f32_16x16x32_bf16(ua[cur], bd0, o, 0, 0, 0);
        o = __builtin_amdgcn_mfma_f32_16x16x32_bf16(ub[cur], bd1, o, 0, 0, 0);
        int dbase = (wid * 32 + i) * 16;
        f32x4 bu = *(const f32x4*)(b_up + dbase + g * 4);
        o += bu;
        *(f32x4*)(outr + dbase + g * 4) = o;
    }
}

extern "C" void kernel_launch(void* const* d_in, const int* in_sizes, int n_in,
                              void* d_out, int out_size, void* d_ws, size_t ws_size,
                              hipStream_t stream) {
    const float* x      = (const float*)d_in[0];
    const float* gamma  = (const float*)d_in[1];
    const float* beta   = (const float*)d_in[2];
    const float* w_down = (const float*)d_in[3];
    const float* b_down = (const float*)d_in[4];
    const float* w_up   = (const float*)d_in[5];
    const float* b_up   = (const float*)d_in[6];
    float* out = (float*)d_out;

    char* ws = (char*)d_ws;
    short* wg_perm  = (short*)ws;                 // 256 KB
    short* wup_perm = (short*)(ws + 262144);      // 256 KB
    float* s_v  = (float*)(ws + 524288);          // 256 B
    float* c_v  = (float*)(ws + 524544);          // 256 B

    prep_kernel<<<128, 256, 0, stream>>>(w_down, gamma, beta, b_down, w_up,
                                         wg_perm, wup_perm, s_v, c_v);
    adapter_kernel<<<1024, 256, 0, stream>>>(x, b_up, wg_perm, wup_perm,
                                             s_v, c_v, out);
}